// Round 6
// baseline (375.593 us; speedup 1.0000x reference)
//
#include <hip/hip_runtime.h>
#include <hip/hip_cooperative_groups.h>
#include <cstring>

namespace cg = cooperative_groups;

#define D 128
#define ROW 16512                 // D + D*D
#define DTF (1.0f/4095.0f)
#define HSTEP (64.0f/4095.0f)     // Zs scale: Zs = (64*dt)*B
#define H4F  (256.0f/4095.0f)     // coarse checkpoint step
#define LDA 132
#define LDB 132

#define XCP_OFF 4096              // x0 vector
#define MAT_OFF 12416

// slot map (each slot = 16384 floats = one 128x128 matrix)
#define S_Z1      0               // Zs
#define S_Z2      1
#define S_Z4      2
#define S_ZT      3               // Zs transposed
#define S_V(m)    (4+(m))         // V_m = W0*Zs^m, m=0..6
#define S_A(J)    (11+(J))        // W(256J), J=0..15
#define S_BM(J)   (27+(J))        // W(256J+128), J=0..14
#define S_K2(J)   (42+(J))
#define S_K3(J)   (57+(J))
#define S_PA      72              // scan ping, 15 matrices
#define S_PB      87              // scan pong

// co-op kernel LDS: As[16][132] (8448 B) + Bs[64][132] (33792 B) = 42240 B
#define SM_BS_OFF   8448
#define SM_CO_BYTES 42240

struct __align__(16) F4 { float v[4]; };
typedef float f4v __attribute__((ext_vector_type(4)));

__device__ __forceinline__ float* slotp(float* ws, int k){ return ws + MAT_OFF + (size_t)k*16384; }
__device__ __forceinline__ const float* slotpc(const float* ws, int k){ return ws + MAT_OFF + (size_t)k*16384; }

struct CFX { float cf[64][5]; float cx[64][7]; };  // M^i (deg4), M^(64j) (deg6), /64^m scaled
struct CMB { float c[31][7]; };                    // rows: A_J (J=0..15), BM_J (J=0..14)
struct EK  { double e[4][4]; };                    // [z^m](M-1)^k / 64^m, k=1..4, m=1..4

// ---------------- matmul pieces (B staged in 64-row halves) ----------------
__device__ __forceinline__ void ldA(const float* A, int r0, float (*As)[LDA]) {
  const F4* A4 = (const F4*)(A + (size_t)r0*128);
  for (int q = threadIdx.x; q < 512; q += 256) {
    F4 x = A4[q];
    *(F4*)&As[q>>5][(q&31)<<2] = x;
  }
}
// load B rows [h*64, h*64+64); mode: B' = scale*B + I
__device__ __forceinline__ void ldB_half(const float* Bsrc, int h, int mode, float scale,
                                         float (*Bs)[LDB]) {
  const F4* B4 = (const F4*)Bsrc;
  for (int q = threadIdx.x; q < 2048; q += 256) {
    int q2 = h*2048 + q;
    F4 x = B4[q2];
    int row = q2 >> 5, c0 = (q2 & 31) << 2;
    F4 o;
    if (mode) {
      #pragma unroll
      for (int e = 0; e < 4; ++e) o.v[e] = scale * x.v[e];
      int de = row - c0;
      if (de >= 0 && de < 4) o.v[de] += 1.0f;
    } else {
      o = x;
    }
    *(F4*)&Bs[row - h*64][c0] = o;
  }
}
__device__ __forceinline__ void mmc_half(const float (*As)[LDA], const float (*Bs)[LDB],
                                         int kb, F4& o0, F4& o1) {
  const int rl = threadIdx.x >> 5, c0 = (threadIdx.x & 31) << 2;
  #pragma unroll 8
  for (int k = 0; k < 64; ++k) {
    const F4 bv = *(const F4*)&Bs[k][c0];
    const float a0 = As[rl][kb+k], a1 = As[rl+8][kb+k];
    #pragma unroll
    for (int e = 0; e < 4; ++e) {
      o0.v[e] = fmaf(a0, bv.v[e], o0.v[e]);
      o1.v[e] = fmaf(a1, bv.v[e], o1.v[e]);
    }
  }
}
// full strip product: o = A[strip rows] * (mode ? I + scale*B : B)
__device__ __forceinline__ void mm_core(char* smb, const float* A, const float* Bsrc,
                                        int strip, int mode, float scale, F4& o0, F4& o1) {
  float (*As)[LDA] = (float (*)[LDA])smb;
  float (*Bs)[LDB] = (float (*)[LDB])(smb + SM_BS_OFF);
  ldA(A, strip*16, As);
  #pragma unroll
  for (int e = 0; e < 4; ++e) { o0.v[e] = 0.f; o1.v[e] = 0.f; }
  #pragma unroll
  for (int h = 0; h < 2; ++h) {
    ldB_half(Bsrc, h, mode, scale, Bs);
    __syncthreads();
    mmc_half(As, Bs, h*64, o0, o1);
    __syncthreads();
  }
}
__device__ __forceinline__ void mm_strip(char* smb, const float* A, const float* Bsrc,
                                         float* Cp, int strip, int mode, float scale) {
  F4 o0, o1;
  mm_core(smb, A, Bsrc, strip, mode, scale, o0, o1);
  int rl = threadIdx.x >> 5, c0 = (threadIdx.x & 31) << 2;
  *(F4*)&Cp[(size_t)(strip*16+rl)*128 + c0]   = o0;
  *(F4*)&Cp[(size_t)(strip*16+rl+8)*128 + c0] = o1;
}

// PhiT[J] strip: transpose( I + h/6*(A_J + 2K2 + 2K3 + A_{J+1}*(I+h K3)) )
__device__ __forceinline__ void f4_strip(char* smb, float* ws, int J, int strip) {
  F4 o0, o1;
  mm_core(smb, slotpc(ws, S_A(J+1)), slotpc(ws, S_K3(J)), strip, 1, H4F, o0, o1);
  const int rl = threadIdx.x >> 5, c0 = (threadIdx.x & 31) << 2;
  const int r0 = strip*16;
  float* PT = slotp(ws, S_PA + J);
  const float h6 = H4F / 6.0f;
  const F4* Xj = (const F4*)slotpc(ws, S_A(J));
  const F4* K2 = (const F4*)slotpc(ws, S_K2(J));
  const F4* K3 = (const F4*)slotpc(ws, S_K3(J));
  #pragma unroll
  for (int half = 0; half < 2; ++half) {
    int r = r0 + rl + half*8;
    F4 o = half ? o1 : o0;
    int q = r*32 + (c0 >> 2);
    F4 xj = Xj[q], k2 = K2[q], k3 = K3[q];
    #pragma unroll
    for (int e = 0; e < 4; ++e) {
      float phi = ((r == c0+e) ? 1.0f : 0.0f)
                + h6*(xj.v[e] + 2.0f*k2.v[e] + 2.0f*k3.v[e] + o.v[e]);
      PT[(size_t)(c0+e)*128 + r] = phi;
    }
  }
}

// scan strip: dst_j = src_{j-shift} * src_j (transposed product), copy if j<shift
__device__ __forceinline__ void scan_strip(char* smb, float* ws, int shift,
                                           int srcBase, int dstBase, int j, int strip) {
  const float* src = slotpc(ws, srcBase + j);
  float* dst = slotp(ws, dstBase + j);
  if (j < shift) {
    const F4* s4 = (const F4*)(src + (size_t)strip*16*128);
    F4* d4 = (F4*)(dst + (size_t)strip*16*128);
    for (int q = threadIdx.x; q < 512; q += 256) d4[q] = s4[q];
    return;
  }
  mm_strip(smb, slotpc(ws, srcBase + j - shift), src, dst, strip, 0, 0.f);
}

// ---------------- unified stage dispatcher (stages S0..S11) ----------------
__device__ void run_stage(int s, int b, char* smb, const float* y0, const float* Bm,
                          float* ws, float* out, const CMB* cmb) {
  const int t = threadIdx.x;
  const float* W0 = y0 + D;
  switch (s) {
  case 0: // prep: Z1, ZT, out row0, x0, V0
    if (b < 16) {
      int q = b*256 + t;
      F4 v = ((const F4*)Bm)[q];
      F4 o;
      #pragma unroll
      for (int e = 0; e < 4; ++e) o.v[e] = HSTEP * v.v[e];
      ((F4*)slotp(ws, S_Z1))[q] = o;
      int r = q >> 5, c0 = (q & 31) << 2;
      float* ZT = slotp(ws, S_ZT);
      #pragma unroll
      for (int e = 0; e < 4; ++e) ZT[(size_t)(c0+e)*128 + r] = o.v[e];
    } else if (b < 32) {
      int q = (b-16)*256 + t;
      ((F4*)out)[q] = ((const F4*)y0)[q];
    } else if (b == 32) {
      if (t < 128) {
        out[16384 + t] = y0[16384 + t];
        ws[XCP_OFF + t] = y0[t];
      }
    } else if (b < 49) {
      int q = (b-33)*256 + t;
      ((F4*)slotp(ws, S_V(0)))[q] = ((const F4*)W0)[q];
    }
    break;
  case 1: // Z2 = Z1*Z1 ; V1 = W0*Z1
    if (b < 8)       mm_strip(smb, slotpc(ws,S_Z1), slotpc(ws,S_Z1), slotp(ws,S_Z2),   b,   0, 0.f);
    else if (b < 16) mm_strip(smb, W0,              slotpc(ws,S_Z1), slotp(ws,S_V(1)), b-8, 0, 0.f);
    break;
  case 2: // Z4 = Z2*Z2 ; V2 = W0*Z2 ; V3 = V1*Z2
    if (b < 8)       mm_strip(smb, slotpc(ws,S_Z2),   slotpc(ws,S_Z2), slotp(ws,S_Z4),   b,    0, 0.f);
    else if (b < 16) mm_strip(smb, W0,                slotpc(ws,S_Z2), slotp(ws,S_V(2)), b-8,  0, 0.f);
    else if (b < 24) mm_strip(smb, slotpc(ws,S_V(1)), slotpc(ws,S_Z2), slotp(ws,S_V(3)), b-16, 0, 0.f);
    break;
  case 3: // V4 = V2*Z2 ; V5 = V3*Z2 ; V6 = V2*Z4
    if (b < 8)       mm_strip(smb, slotpc(ws,S_V(2)), slotpc(ws,S_Z2), slotp(ws,S_V(4)), b,    0, 0.f);
    else if (b < 16) mm_strip(smb, slotpc(ws,S_V(3)), slotpc(ws,S_Z2), slotp(ws,S_V(5)), b-8,  0, 0.f);
    else if (b < 24) mm_strip(smb, slotpc(ws,S_V(2)), slotpc(ws,S_Z4), slotp(ws,S_V(6)), b-16, 0, 0.f);
    break;
  case 4: // comb: A_J (idx 0..15), BM_J (idx 16..30)
    if (b < 62) {
      int idx = b >> 1, half = b & 1;
      int slot = (idx < 16) ? (S_A(0) + idx) : (S_BM(0) + idx - 16);
      float cr[7];
      #pragma unroll
      for (int m = 0; m < 7; ++m) cr[m] = cmb->c[idx][m];
      F4* Xp = (F4*)slotp(ws, slot) + half*2048;
      const F4* Vp[7];
      #pragma unroll
      for (int m = 0; m < 7; ++m) Vp[m] = (const F4*)slotpc(ws, S_V(m)) + half*2048;
      for (int q = t; q < 2048; q += 256) {
        F4 acc;
        #pragma unroll
        for (int e = 0; e < 4; ++e) acc.v[e] = 0.f;
        #pragma unroll
        for (int m = 0; m < 7; ++m) {
          F4 x = Vp[m][q];
          #pragma unroll
          for (int e = 0; e < 4; ++e) acc.v[e] = fmaf(cr[m], x.v[e], acc.v[e]);
        }
        Xp[q] = acc;
      }
    }
    break;
  case 5: // K2 = BM*(I + h/2 A)
    if (b < 120) mm_strip(smb, slotpc(ws,S_BM(b>>3)), slotpc(ws,S_A(b>>3)),  slotp(ws,S_K2(b>>3)), b&7, 1, 0.5f*H4F);
    break;
  case 6: // K3 = BM*(I + h/2 K2)
    if (b < 120) mm_strip(smb, slotpc(ws,S_BM(b>>3)), slotpc(ws,S_K2(b>>3)), slotp(ws,S_K3(b>>3)), b&7, 1, 0.5f*H4F);
    break;
  case 7: // PhiT
    if (b < 120) f4_strip(smb, ws, b>>3, b&7);
    break;
  case 8:  if (b < 120) scan_strip(smb, ws, 1, S_PA, S_PB, b>>3, b&7); break;
  case 9:  if (b < 120) scan_strip(smb, ws, 2, S_PB, S_PA, b>>3, b&7); break;
  case 10: if (b < 120) scan_strip(smb, ws, 4, S_PA, S_PB, b>>3, b&7); break;
  case 11: if (b < 120) scan_strip(smb, ws, 8, S_PB, S_PA, b>>3, b&7); break;
  }
}

// ---------------- cooperative fused kernel (42 KB LDS) ----------------
__global__ __launch_bounds__(256) void k_coop(const float* y0, const float* Bm,
                                              float* ws, float* out, CMB cmb) {
  cg::grid_group grid = cg::this_grid();
  __shared__ __align__(16) char smb[SM_CO_BYTES];
  run_stage(0, blockIdx.x, smb, y0, Bm, ws, out, &cmb);
  #pragma unroll 1
  for (int s = 1; s <= 11; ++s) {
    grid.sync();
    run_stage(s, blockIdx.x, smb, y0, Bm, ws, out, &cmb);
  }
}

// fallback: one stage per normal launch
__global__ __launch_bounds__(256) void k_stage(int s, const float* y0, const float* Bm,
                                               float* ws, float* out, CMB cmb) {
  __shared__ __align__(16) char smb[SM_CO_BYTES];
  run_stage(s, blockIdx.x, smb, y0, Bm, ws, out, &cmb);
}

// x fill: per block (J, w): checkpoint matvec + Heun jumps for i = w*64 + il
__global__ __launch_bounds__(256) void k_phase2(float* ws, float* out, EK ek) {
  __shared__ float XT[128][129];
  __shared__ float uni[128*68];     // U[c][il]
  __shared__ float za[5][128], zb[5][128];
  __shared__ float kv[128], xv[128], red[128], xs0[128];
  __shared__ float cfs[64][5];
  int b = blockIdx.x, t = threadIdx.x;
  int J = b >> 2, w = b & 3;
  {
    const F4* Xg = (const F4*)slotpc(ws, S_A(J));
    for (int q = t; q < 4096; q += 256) {
      F4 x = Xg[q]; int r = q >> 5, c0 = (q & 31) << 2;
      #pragma unroll
      for (int e = 0; e < 4; ++e) XT[c0+e][r] = x.v[e];
    }
    if (t < 64) { // cfs[il][m] = [Zs^m] M^(w*64+il), closed form via binomials
      double di = (double)(w*64 + t);
      double b1 = di, b2 = b1*(di-1.0)*0.5, b3 = b2*(di-2.0)*(1.0/3.0), b4 = b3*(di-3.0)*0.25;
      cfs[t][0] = 1.f;
      cfs[t][1] = (float)(b1*ek.e[0][0]);
      cfs[t][2] = (float)(b1*ek.e[0][1] + b2*ek.e[1][1]);
      cfs[t][3] = (float)(b1*ek.e[0][2] + b2*ek.e[1][2] + b3*ek.e[2][2]);
      cfs[t][4] = (float)(b1*ek.e[0][3] + b2*ek.e[1][3] + b3*ek.e[2][3] + b4*ek.e[3][3]);
    }
    if (t < 128) xs0[t] = ws[XCP_OFF + t];
  }
  __syncthreads();
  int r = t & 127, hh = t >> 7;
  if (J > 0) { // xv = Psi_{J-1} x0
    const float* PT = slotpc(ws, S_PA + J - 1);
    float s = 0.f;
    #pragma unroll 8
    for (int c = hh*64; c < hh*64 + 64; ++c) s = fmaf(PT[(size_t)c*128 + r], xs0[c], s);
    if (hh) red[r] = s;
    __syncthreads();
    if (!hh) {
      float nx = s + red[r];
      xv[r] = nx;
      if (w == 0) out[(size_t)(256*J)*ROW + r] = nx;
    }
  } else if (t < 128) {
    xv[t] = xs0[t];
  }
  __syncthreads();
  { // k1 = A_J * xv
    float s = 0.f;
    for (int c = hh*64; c < hh*64 + 64; ++c) s = fmaf(XT[c][r], xv[c], s);
    if (hh) red[r] = s;
    __syncthreads();
    if (!hh) kv[r] = s + red[r];
    __syncthreads();
  }
  if (t < 128) { za[0][t] = xv[t]; zb[0][t] = kv[t]; }
  __syncthreads();
  const float* ZTg = slotpc(ws, S_ZT);
  for (int m = 1; m <= 4; ++m) {
    float sa = 0.f, sb = 0.f;
    for (int c = hh*64; c < hh*64 + 64; ++c) {
      float zv = ZTg[(size_t)c*128 + r];
      sa = fmaf(zv, za[m-1][c], sa);
      sb = fmaf(zv, zb[m-1][c], sb);
    }
    if (hh) red[r] = sa;
    __syncthreads();
    if (!hh) za[m][r] = sa + red[r];
    __syncthreads();
    if (hh) red[r] = sb;
    __syncthreads();
    if (!hh) zb[m][r] = sb + red[r];
    __syncthreads();
  }
  // U[c][il] = M^i (xv + h_i k1), i = w*64 + il
  for (int idx = t; idx < 64*128; idx += 256) {
    int il = idx >> 7, c = idx & 127;
    int i = w*64 + il;
    float val = 0.f;
    if (i >= 1) {
      float hi = i * DTF;
      #pragma unroll
      for (int m = 0; m <= 4; ++m) val = fmaf(cfs[il][m], za[m][c] + hi*zb[m][c], val);
    }
    uni[c*68 + il] = val;
  }
  __syncthreads();
  // k2[r][il] = sum_c A_J[r][c] U[c][il]
  int rg = t >> 4, i0 = (t & 15) << 2;
  F4 acc[8];
  #pragma unroll
  for (int k = 0; k < 8; ++k)
    #pragma unroll
    for (int e = 0; e < 4; ++e) acc[k].v[e] = 0.f;
  for (int c = 0; c < 128; ++c) {
    F4 bvv = *(const F4*)&uni[c*68 + i0];
    #pragma unroll
    for (int k = 0; k < 8; ++k) {
      float a = XT[c][rg + 16*k];
      #pragma unroll
      for (int e = 0; e < 4; ++e) acc[k].v[e] = fmaf(a, bvv.v[e], acc[k].v[e]);
    }
  }
  #pragma unroll
  for (int k = 0; k < 8; ++k) {
    int rr = rg + 16*k;
    float xr = xv[rr], kr = kv[rr];
    #pragma unroll
    for (int e = 0; e < 4; ++e) {
      int il = i0 + e;
      int i = w*64 + il;
      if (i >= 1) {
        float hi = i * DTF;
        out[(size_t)(256*J + i)*ROW + rr] = xr + 0.5f*hi*(kr + acc[k].v[e]);
      }
    }
  }
}

// W fill: W_{64j+i} = sum_{p=0..6} conv(cf[i],cx[j])[p] * V_p  (write-bound)
__global__ __launch_bounds__(256) void k_fill(const float* ws, float* out, CFX cc) {
  __shared__ float coefL[64][7];
  int t = threadIdx.x;
  int j = blockIdx.x >> 4, strip = blockIdx.x & 15;
  for (int idx = t; idx < 448; idx += 256) {
    int i = idx / 7, p = idx - i*7;
    float s = 0.f;
    #pragma unroll
    for (int m = 0; m <= 4; ++m) {
      int q = p - m;
      float cxv = (q >= 0) ? cc.cx[j][q] : 0.f;
      s = fmaf(cc.cf[i][m], cxv, s);
    }
    coefL[i][p] = s;
  }
  int r = strip*8 + (t >> 5);
  int q = r*32 + (t & 31);
  F4 v[7];
  #pragma unroll
  for (int m = 0; m < 7; ++m) v[m] = ((const F4*)slotpc(ws, S_V(m)))[q];
  __syncthreads();
  for (int i = 0; i < 64; ++i) {
    f4v o = {0.f, 0.f, 0.f, 0.f};
    #pragma unroll
    for (int p = 0; p < 7; ++p) {
      float c = coefL[i][p];
      #pragma unroll
      for (int e = 0; e < 4; ++e) o[e] = fmaf(c, v[p].v[e], o[e]);
    }
    __builtin_nontemporal_store(o, (f4v*)(out + (size_t)(j*64 + i)*ROW + D + q*4));
  }
}

// ---------------- host ----------------
static void pmul16(const double* a, const double* b, double* o) {
  double r[16];
  for (int i = 0; i < 16; ++i) r[i] = 0.0;
  for (int i = 0; i < 16; ++i) {
    double ai = a[i];
    if (ai == 0.0) continue;
    for (int k = 0; i + k < 16; ++k) r[i+k] += ai*b[k];
  }
  for (int i = 0; i < 16; ++i) o[i] = r[i];
}

extern "C" void kernel_launch(void* const* d_in, const int* in_sizes, int n_in,
                              void* d_out, int out_size, void* d_ws, size_t ws_size,
                              hipStream_t stream) {
  (void)in_sizes; (void)n_in; (void)out_size; (void)ws_size;
  const float* y0 = (const float*)d_in[1];
  const float* Bm = (const float*)d_in[2];
  float* out = (float*)d_out;
  float* ws  = (float*)d_ws;

  // Tsit5 stability polynomial M(z), z = dt*B, via C_s recurrence
  double At[7][7]; memset(At, 0, sizeof(At));
  At[2][1] = 0.161;
  At[3][1] = -0.008480655492356989; At[3][2] = 0.335480655492357;
  At[4][1] = 2.8971530571054935;  At[4][2] = -6.359448489975075;  At[4][3] = 4.3622954328695815;
  At[5][1] = 5.325864828439257;   At[5][2] = -11.748883564062828; At[5][3] = 7.4955393428898365;  At[5][4] = -0.09249506636175525;
  At[6][1] = 5.86145544294642;    At[6][2] = -12.92096931784711;  At[6][3] = 8.159367898576159;   At[6][4] = -0.071584973281401; At[6][5] = -0.028269050394068383;
  const double dB[7] = {0, 0.09646076681806523, 0.01, 0.4798896504144996,
                        1.379008574103742, -3.290069515436081, 2.324710524099774};
  double C[7][16]; memset(C, 0, sizeof(C));
  C[1][0] = 1.0;
  for (int s = 2; s <= 6; ++s) {
    C[s][0] = 1.0;
    for (int k = 1; k < 16; ++k) {
      double acc = 0.0;
      for (int l = 1; l < s; ++l) acc += At[s][l]*C[l][k-1];
      C[s][k] = acc;
    }
  }
  double M[16]; memset(M, 0, sizeof(M)); M[0] = 1.0;
  for (int k = 1; k < 16; ++k) {
    double acc = 0.0;
    for (int s = 1; s <= 6; ++s) acc += dB[s]*C[s][k-1];
    M[k] = acc;
  }
  double p64m[16]; p64m[0] = 1.0;
  for (int m = 1; m < 16; ++m) p64m[m] = p64m[m-1]*64.0;

  // harvest scaled coefficient rows of M^n along one pmul chain
  CFX cfx; memset(&cfx, 0, sizeof(cfx));
  CMB cmb; memset(&cmb, 0, sizeof(cmb));
  double cur[16]; memset(cur, 0, sizeof(cur)); cur[0] = 1.0;
  for (int n = 0; n <= 4032; ++n) {
    if (n < 64)  for (int m = 0; m <= 4; ++m) cfx.cf[n][m] = (float)(cur[m]/p64m[m]);
    if ((n & 63) == 0) {
      int j = n >> 6;
      if (j < 64) for (int m = 0; m <= 6; ++m) cfx.cx[j][m] = (float)(cur[m]/p64m[m]);
    }
    if ((n & 255) == 0) {
      int J = n >> 8;
      if (J <= 15) for (int m = 0; m <= 6; ++m) cmb.c[J][m] = (float)(cur[m]/p64m[m]);
    }
    if ((n & 255) == 128) {
      int J = (n - 128) >> 8;
      if (J <= 14) for (int m = 0; m <= 6; ++m) cmb.c[16+J][m] = (float)(cur[m]/p64m[m]);
    }
    pmul16(cur, M, cur);
  }

  // EK: [z^m](M-1)^k / 64^m for phase2's closed-form M^i coefficients
  EK ek; memset(&ek, 0, sizeof(ek));
  {
    double e1[5] = {0,0,0,0,0}, e2[5] = {0,0,0,0,0}, e3[5] = {0,0,0,0,0}, e4[5] = {0,0,0,0,0};
    for (int m = 1; m <= 4; ++m) e1[m] = M[m];
    for (int m = 2; m <= 4; ++m) for (int a = 1; a < m; ++a) e2[m] += e1[a]*e1[m-a];
    for (int m = 3; m <= 4; ++m) for (int a = 2; a < m; ++a) e3[m] += e2[a]*e1[m-a];
    e4[4] = e3[3]*e1[1];
    for (int m = 1; m <= 4; ++m) {
      ek.e[0][m-1] = e1[m]/p64m[m];
      ek.e[1][m-1] = e2[m]/p64m[m];
      ek.e[2][m-1] = e3[m]/p64m[m];
      ek.e[3][m-1] = e4[m]/p64m[m];
    }
  }

  // fused cooperative x-path kernel; fall back to per-stage launches on failure
  {
    const float* y0a = y0; const float* Bma = Bm; float* wsa = ws; float* outa = out;
    void* args[5] = { (void*)&y0a, (void*)&Bma, (void*)&wsa, (void*)&outa, (void*)&cmb };
    hipError_t cerr = hipLaunchCooperativeKernel((const void*)k_coop, dim3(120), dim3(256),
                                                 args, 0, stream);
    if (cerr != hipSuccess) {
      (void)hipGetLastError();  // clear sticky error state
      static const int grids[12] = {49,16,24,24,62,120,120,120,120,120,120,120};
      for (int s = 0; s < 12; ++s)
        k_stage<<<grids[s], 256, 0, stream>>>(s, y0, Bm, ws, out, cmb);
    }
  }

  k_phase2<<<64, 256, 0, stream>>>(ws, out, ek);
  k_fill<<<1024, 256, 0, stream>>>(ws, out, cfx);
}

// Round 7
// 175.112 us; speedup vs baseline: 2.1449x; 2.1449x over previous
//
#include <hip/hip_runtime.h>
#include <cstring>

#define D 128
#define ROW 16512                 // D + D*D
#define DTF (1.0f/4095.0f)
#define HSTEP (64.0f/4095.0f)     // Zs scale: Zs = (64*dt)*B
#define H4F  (256.0f/4095.0f)     // coarse checkpoint step
#define LDA 132
#define LDB 132
#define LDBP 128

#define XCP_OFF 4096              // x0 vector
#define MAT_OFF 12416

// slot map (each slot = 16384 floats = one 128x128 matrix)
#define S_ZT      3               // Zs transposed
#define S_V(m)    (4+(m))         // V_m = W0*Zs^m, m=0..6
#define S_A(J)    (11+(J))        // W(256J), J=0..15
#define S_BM(J)   (27+(J))        // W(256J+128), J=0..14
#define S_PA      72              // PhiT_J, J=0..14

struct __align__(16) F4 { float v[4]; };
typedef float f4v __attribute__((ext_vector_type(4)));

__device__ __forceinline__ float* slotp(float* ws, int k){ return ws + MAT_OFF + (size_t)k*16384; }
__device__ __forceinline__ const float* slotpc(const float* ws, int k){ return ws + MAT_OFF + (size_t)k*16384; }

struct CFX { float cf[64][5]; float cx[64][7]; };  // M^i (deg4), M^(64j) (deg6), /64^m scaled
struct CMB { float c[31][7]; };                    // rows: A_J (J=0..15), BM_J (J=0..14)
struct EK  { double e[4][4]; };                    // [z^m](M-1)^k / 64^m, k=1..4, m=1..4

// ---------------- 256-thread strip-matmul pieces ----------------
__device__ __forceinline__ void ldA(const float* A, int r0, float (*As)[LDA]) {
  const F4* A4 = (const F4*)(A + (size_t)r0*128);
  for (int q = threadIdx.x; q < 512; q += 256) {
    F4 x = A4[q];
    *(F4*)&As[q>>5][(q&31)<<2] = x;
  }
}
template <int LB>
__device__ __forceinline__ void mmcT(const float (*As)[LDA], const float (*Bs)[LB], F4& o0, F4& o1) {
  const int rl = threadIdx.x >> 5, c0 = (threadIdx.x & 31) << 2;
  F4 a0s, a1s;
  #pragma unroll
  for (int e = 0; e < 4; ++e) { a0s.v[e] = 0.f; a1s.v[e] = 0.f; }
  #pragma unroll 8
  for (int k = 0; k < 128; ++k) {
    const F4 bv = *(const F4*)&Bs[k][c0];
    const float a0 = As[rl][k], a1 = As[rl+8][k];
    #pragma unroll
    for (int e = 0; e < 4; ++e) {
      a0s.v[e] = fmaf(a0, bv.v[e], a0s.v[e]);
      a1s.v[e] = fmaf(a1, bv.v[e], a1s.v[e]);
    }
  }
  o0 = a0s; o1 = a1s;
}

// ---------------- launch 1: V-chain + misc + Horner A/BM ----------------
// blocks 0..47:  (m=1..6, strip): V_m strip = W0_strip * Zs^m  (serial powers, Zs staged once)
// blocks 48..52: out row0 copy + x0
// blocks 53..56: V0 copy
// blocks 57..60: ZT
// blocks 61..308:(mat=0..30, strip): A/BM strip = W0_strip * p_mat(Zs) via Horner
__global__ __launch_bounds__(256) void k_vchain(const float* y0, const float* Bm,
                                                float* ws, float* out, CMB cmb) {
  __shared__ float As[16][LDA];
  __shared__ float Bs[128][LDB];
  int b = blockIdx.x, t = threadIdx.x;
  const float* W0 = y0 + D;
  const int rl = t >> 5, c0 = (t & 31) << 2;
  if (b < 48) {
    int m = (b >> 3) + 1, strip = b & 7;
    const F4* B4 = (const F4*)Bm;
    for (int q = t; q < 4096; q += 256) {
      F4 x = B4[q]; F4 o;
      #pragma unroll
      for (int e = 0; e < 4; ++e) o.v[e] = HSTEP * x.v[e];
      *(F4*)&Bs[q>>5][(q&31)<<2] = o;
    }
    ldA(W0, strip*16, As);
    __syncthreads();
    F4 o0, o1;
    for (int p = 0; p < m; ++p) {
      mmcT<LDB>(As, Bs, o0, o1);
      if (p+1 < m) {
        __syncthreads();
        *(F4*)&As[rl][c0] = o0;
        *(F4*)&As[rl+8][c0] = o1;
        __syncthreads();
      }
    }
    float* Vp = slotp(ws, S_V(m));
    *(F4*)&Vp[(size_t)(strip*16+rl)*128 + c0]   = o0;
    *(F4*)&Vp[(size_t)(strip*16+rl+8)*128 + c0] = o1;
  } else if (b < 52) {
    int base = (b-48)*1024;
    for (int i = 0; i < 4; ++i) {
      int q = base + t + i*256;
      ((F4*)out)[q] = ((const F4*)y0)[q];
    }
  } else if (b == 52) {
    if (t < 128) { out[16384+t] = y0[16384+t]; ws[XCP_OFF+t] = y0[t]; }
  } else if (b < 57) {
    int base = (b-53)*1024;
    F4* Vp = (F4*)slotp(ws, S_V(0));
    for (int i = 0; i < 4; ++i) { int q = base + t + i*256; Vp[q] = ((const F4*)W0)[q]; }
  } else if (b < 61) {
    int base = (b-57)*1024;
    float* ZT = slotp(ws, S_ZT);
    for (int i = 0; i < 4; ++i) {
      int q = base + t + i*256;
      F4 x = ((const F4*)Bm)[q];
      int r = q>>5, cc2 = (q&31)<<2;
      #pragma unroll
      for (int e = 0; e < 4; ++e) ZT[(size_t)(cc2+e)*128 + r] = HSTEP * x.v[e];
    }
  } else {
    int idx = b - 61;
    int mat = idx >> 3, strip = idx & 7;
    int slot = (mat < 16) ? S_A(mat) : S_BM(mat-16);
    const float* cc = cmb.c[mat];
    const F4* B4 = (const F4*)Bm;
    for (int q = t; q < 4096; q += 256) {
      F4 x = B4[q]; F4 o;
      #pragma unroll
      for (int e = 0; e < 4; ++e) o.v[e] = HSTEP * x.v[e];
      *(F4*)&Bs[q>>5][(q&31)<<2] = o;
    }
    const F4 s0 = *(const F4*)&W0[(size_t)(strip*16+rl)*128 + c0];
    const F4 s1 = *(const F4*)&W0[(size_t)(strip*16+rl+8)*128 + c0];
    F4 t0, t1;
    #pragma unroll
    for (int e = 0; e < 4; ++e) { t0.v[e] = cc[6]*s0.v[e]; t1.v[e] = cc[6]*s1.v[e]; }
    *(F4*)&As[rl][c0] = t0; *(F4*)&As[rl+8][c0] = t1;
    __syncthreads();
    F4 o0, o1;
    for (int k = 5; k >= 0; --k) {
      mmcT<LDB>(As, Bs, o0, o1);
      #pragma unroll
      for (int e = 0; e < 4; ++e) { o0.v[e] += cc[k]*s0.v[e]; o1.v[e] += cc[k]*s1.v[e]; }
      if (k > 0) {
        __syncthreads();
        *(F4*)&As[rl][c0] = o0; *(F4*)&As[rl+8][c0] = o1;
        __syncthreads();
      }
    }
    float* Cp = slotp(ws, slot);
    *(F4*)&Cp[(size_t)(strip*16+rl)*128 + c0]   = o0;
    *(F4*)&Cp[(size_t)(strip*16+rl+8)*128 + c0] = o1;
  }
}

// ---------------- launch 2: PhiT_J in one shot (polynomial RK4 expansion) ----------------
// Phi = I + (h/6)[A + 4M + A' + h(MA + M^2 + A'M) + (h^2/2)(M^2 A + A'M^2) + (h^3/4) A'M^2 A]
__global__ __launch_bounds__(256) void k_phi(float* ws) {
  __shared__ float Bs1[128][LDBP];  // BM_J
  __shared__ float Bs2[128][LDBP];  // A_J
  __shared__ float Abm[16][LDA];    // BM strip -> later u2
  __shared__ float Aap[16][LDA];    // A' strip
  __shared__ float Aw[16][LDA];     // working
  int J = blockIdx.x >> 3, strip = blockIdx.x & 7, t = threadIdx.x;
  const int rl = t >> 5, c0 = (t & 31) << 2;
  const float* BM = slotpc(ws, S_BM(J));
  const float* Aj = slotpc(ws, S_A(J));
  const float* Ap = slotpc(ws, S_A(J+1));
  { const F4* s = (const F4*)BM; for (int q=t;q<4096;q+=256) *(F4*)&Bs1[q>>5][(q&31)<<2] = s[q]; }
  { const F4* s = (const F4*)Aj; for (int q=t;q<4096;q+=256) *(F4*)&Bs2[q>>5][(q&31)<<2] = s[q]; }
  ldA(BM, strip*16, Abm);
  ldA(Ap, strip*16, Aap);
  __syncthreads();
  F4 pa0, pa1;
  {
    const F4 a0 = *(const F4*)&Aj[(size_t)(strip*16+rl)*128 + c0];
    const F4 a1 = *(const F4*)&Aj[(size_t)(strip*16+rl+8)*128 + c0];
    #pragma unroll
    for (int e = 0; e < 4; ++e) {
      pa0.v[e] = a0.v[e] + 4.f*Abm[rl][c0+e]   + Aap[rl][c0+e];
      pa1.v[e] = a1.v[e] + 4.f*Abm[rl+8][c0+e] + Aap[rl+8][c0+e];
    }
  }
  const float h = H4F, wh = h, wh2 = 0.5f*h*h, wh3 = 0.25f*h*h*h;
  F4 o0, o1;
  // 1: t2 = BM_s * BM
  mmcT<LDBP>(Abm, Bs1, o0, o1);
  #pragma unroll
  for (int e = 0; e < 4; ++e) { pa0.v[e] += wh*o0.v[e]; pa1.v[e] += wh*o1.v[e]; }
  __syncthreads();
  *(F4*)&Aw[rl][c0] = o0; *(F4*)&Aw[rl+8][c0] = o1;
  __syncthreads();
  // 2: v1 = BM_s * A
  mmcT<LDBP>(Abm, Bs2, o0, o1);
  #pragma unroll
  for (int e = 0; e < 4; ++e) { pa0.v[e] += wh*o0.v[e]; pa1.v[e] += wh*o1.v[e]; }
  // 3: t3 = t2 * A
  mmcT<LDBP>(Aw, Bs2, o0, o1);
  #pragma unroll
  for (int e = 0; e < 4; ++e) { pa0.v[e] += wh2*o0.v[e]; pa1.v[e] += wh2*o1.v[e]; }
  __syncthreads();
  // 4: u1 = A'_s * BM
  mmcT<LDBP>(Aap, Bs1, o0, o1);
  #pragma unroll
  for (int e = 0; e < 4; ++e) { pa0.v[e] += wh*o0.v[e]; pa1.v[e] += wh*o1.v[e]; }
  *(F4*)&Aw[rl][c0] = o0; *(F4*)&Aw[rl+8][c0] = o1;
  __syncthreads();
  // 5: u2 = u1 * BM
  mmcT<LDBP>(Aw, Bs1, o0, o1);
  #pragma unroll
  for (int e = 0; e < 4; ++e) { pa0.v[e] += wh2*o0.v[e]; pa1.v[e] += wh2*o1.v[e]; }
  __syncthreads();
  *(F4*)&Abm[rl][c0] = o0; *(F4*)&Abm[rl+8][c0] = o1;
  __syncthreads();
  // 6: u3 = u2 * A
  mmcT<LDBP>(Abm, Bs2, o0, o1);
  #pragma unroll
  for (int e = 0; e < 4; ++e) { pa0.v[e] += wh3*o0.v[e]; pa1.v[e] += wh3*o1.v[e]; }
  // write transposed PhiT
  float* PT = slotp(ws, S_PA + J);
  const float h6 = h / 6.0f;
  #pragma unroll
  for (int half = 0; half < 2; ++half) {
    int r = strip*16 + rl + half*8;
    F4 pa = half ? pa1 : pa0;
    #pragma unroll
    for (int e = 0; e < 4; ++e) {
      int c = c0 + e;
      float phi = ((r == c) ? 1.0f : 0.0f) + h6*pa.v[e];
      PT[(size_t)c*128 + r] = phi;
    }
  }
}

// ---------------- launch 3: x fill (serial checkpoint chain + Heun jumps) ----------------
__global__ __launch_bounds__(256) void k_phase2(float* ws, float* out, EK ek) {
  __shared__ float XT[128][129];
  __shared__ float uni[128*68];     // U[c][il]
  __shared__ float za[5][128], zb[5][128];
  __shared__ float kv[128], xv[128], red[128], xs0[128];
  __shared__ float cfs[64][5];
  int b = blockIdx.x, t = threadIdx.x;
  int J = b >> 2, w = b & 3;
  {
    const F4* Xg = (const F4*)slotpc(ws, S_A(J));
    for (int q = t; q < 4096; q += 256) {
      F4 x = Xg[q]; int r = q >> 5, cc = (q & 31) << 2;
      #pragma unroll
      for (int e = 0; e < 4; ++e) XT[cc+e][r] = x.v[e];
    }
    if (t < 64) { // cfs[il][m] = [Zs^m] M^(w*64+il), closed form via binomials
      double di = (double)(w*64 + t);
      double b1 = di, b2 = b1*(di-1.0)*0.5, b3 = b2*(di-2.0)*(1.0/3.0), b4 = b3*(di-3.0)*0.25;
      cfs[t][0] = 1.f;
      cfs[t][1] = (float)(b1*ek.e[0][0]);
      cfs[t][2] = (float)(b1*ek.e[0][1] + b2*ek.e[1][1]);
      cfs[t][3] = (float)(b1*ek.e[0][2] + b2*ek.e[1][2] + b3*ek.e[2][2]);
      cfs[t][4] = (float)(b1*ek.e[0][3] + b2*ek.e[1][3] + b3*ek.e[2][3] + b4*ek.e[3][3]);
    }
    if (t < 128) { xs0[t] = ws[XCP_OFF + t]; xv[t] = xs0[t]; }
  }
  __syncthreads();
  int r = t & 127, hh = t >> 7;
  // serial checkpoint chain: xv = Phi_{J-1} ... Phi_0 x0
  for (int jj = 0; jj < J; ++jj) {
    const float* PT = slotpc(ws, S_PA + jj);
    float s = 0.f;
    #pragma unroll 8
    for (int c = hh*64; c < hh*64 + 64; ++c) s = fmaf(PT[(size_t)c*128 + r], xv[c], s);
    if (hh) red[r] = s;
    __syncthreads();
    if (!hh) xv[r] = s + red[r];
    __syncthreads();
  }
  if (J > 0 && w == 0 && t < 128) out[(size_t)(256*J)*ROW + t] = xv[t];
  { // k1 = A_J * xv
    float s = 0.f;
    for (int c = hh*64; c < hh*64 + 64; ++c) s = fmaf(XT[c][r], xv[c], s);
    if (hh) red[r] = s;
    __syncthreads();
    if (!hh) kv[r] = s + red[r];
    __syncthreads();
  }
  if (t < 128) { za[0][t] = xv[t]; zb[0][t] = kv[t]; }
  __syncthreads();
  const float* ZTg = slotpc(ws, S_ZT);
  for (int m = 1; m <= 4; ++m) {
    float sa = 0.f, sb = 0.f;
    for (int c = hh*64; c < hh*64 + 64; ++c) {
      float zv = ZTg[(size_t)c*128 + r];
      sa = fmaf(zv, za[m-1][c], sa);
      sb = fmaf(zv, zb[m-1][c], sb);
    }
    if (hh) red[r] = sa;
    __syncthreads();
    if (!hh) za[m][r] = sa + red[r];
    __syncthreads();
    if (hh) red[r] = sb;
    __syncthreads();
    if (!hh) zb[m][r] = sb + red[r];
    __syncthreads();
  }
  // U[c][il] = M^i (xv + h_i k1), i = w*64 + il
  for (int idx = t; idx < 64*128; idx += 256) {
    int il = idx >> 7, c = idx & 127;
    int i = w*64 + il;
    float val = 0.f;
    if (i >= 1) {
      float hi = i * DTF;
      #pragma unroll
      for (int m = 0; m <= 4; ++m) val = fmaf(cfs[il][m], za[m][c] + hi*zb[m][c], val);
    }
    uni[c*68 + il] = val;
  }
  __syncthreads();
  // k2[r][il] = sum_c A_J[r][c] U[c][il]
  int rg = t >> 4, i0 = (t & 15) << 2;
  F4 acc[8];
  #pragma unroll
  for (int k = 0; k < 8; ++k)
    #pragma unroll
    for (int e = 0; e < 4; ++e) acc[k].v[e] = 0.f;
  for (int c = 0; c < 128; ++c) {
    F4 bvv = *(const F4*)&uni[c*68 + i0];
    #pragma unroll
    for (int k = 0; k < 8; ++k) {
      float a = XT[c][rg + 16*k];
      #pragma unroll
      for (int e = 0; e < 4; ++e) acc[k].v[e] = fmaf(a, bvv.v[e], acc[k].v[e]);
    }
  }
  #pragma unroll
  for (int k = 0; k < 8; ++k) {
    int rr = rg + 16*k;
    float xr = xv[rr], kr = kv[rr];
    #pragma unroll
    for (int e = 0; e < 4; ++e) {
      int il = i0 + e;
      int i = w*64 + il;
      if (i >= 1) {
        float hi = i * DTF;
        out[(size_t)(256*J + i)*ROW + rr] = xr + 0.5f*hi*(kr + acc[k].v[e]);
      }
    }
  }
}

// ---------------- launch 4: W fill (write-bound) ----------------
__global__ __launch_bounds__(256) void k_fill(const float* ws, float* out, CFX cc) {
  __shared__ float coefL[64][7];
  int t = threadIdx.x;
  int j = blockIdx.x >> 4, strip = blockIdx.x & 15;
  for (int idx = t; idx < 448; idx += 256) {
    int i = idx / 7, p = idx - i*7;
    float s = 0.f;
    #pragma unroll
    for (int m = 0; m <= 4; ++m) {
      int q = p - m;
      float cxv = (q >= 0) ? cc.cx[j][q] : 0.f;
      s = fmaf(cc.cf[i][m], cxv, s);
    }
    coefL[i][p] = s;
  }
  int r = strip*8 + (t >> 5);
  int q = r*32 + (t & 31);
  F4 v[7];
  #pragma unroll
  for (int m = 0; m < 7; ++m) v[m] = ((const F4*)slotpc(ws, S_V(m)))[q];
  __syncthreads();
  for (int i = 0; i < 64; ++i) {
    f4v o = {0.f, 0.f, 0.f, 0.f};
    #pragma unroll
    for (int p = 0; p < 7; ++p) {
      float c = coefL[i][p];
      #pragma unroll
      for (int e = 0; e < 4; ++e) o[e] = fmaf(c, v[p].v[e], o[e]);
    }
    __builtin_nontemporal_store(o, (f4v*)(out + (size_t)(j*64 + i)*ROW + D + q*4));
  }
}

// ---------------- host ----------------
static void pmul16(const double* a, const double* b, double* o) {
  double r[16];
  for (int i = 0; i < 16; ++i) r[i] = 0.0;
  for (int i = 0; i < 16; ++i) {
    double ai = a[i];
    if (ai == 0.0) continue;
    for (int k = 0; i + k < 16; ++k) r[i+k] += ai*b[k];
  }
  for (int i = 0; i < 16; ++i) o[i] = r[i];
}

extern "C" void kernel_launch(void* const* d_in, const int* in_sizes, int n_in,
                              void* d_out, int out_size, void* d_ws, size_t ws_size,
                              hipStream_t stream) {
  (void)in_sizes; (void)n_in; (void)out_size; (void)ws_size;
  const float* y0 = (const float*)d_in[1];
  const float* Bm = (const float*)d_in[2];
  float* out = (float*)d_out;
  float* ws  = (float*)d_ws;

  // Tsit5 stability polynomial M(z), z = dt*B, via C_s recurrence
  double At[7][7]; memset(At, 0, sizeof(At));
  At[2][1] = 0.161;
  At[3][1] = -0.008480655492356989; At[3][2] = 0.335480655492357;
  At[4][1] = 2.8971530571054935;  At[4][2] = -6.359448489975075;  At[4][3] = 4.3622954328695815;
  At[5][1] = 5.325864828439257;   At[5][2] = -11.748883564062828; At[5][3] = 7.4955393428898365;  At[5][4] = -0.09249506636175525;
  At[6][1] = 5.86145544294642;    At[6][2] = -12.92096931784711;  At[6][3] = 8.159367898576159;   At[6][4] = -0.071584973281401; At[6][5] = -0.028269050394068383;
  const double dB[7] = {0, 0.09646076681806523, 0.01, 0.4798896504144996,
                        1.379008574103742, -3.290069515436081, 2.324710524099774};
  double C[7][16]; memset(C, 0, sizeof(C));
  C[1][0] = 1.0;
  for (int s = 2; s <= 6; ++s) {
    C[s][0] = 1.0;
    for (int k = 1; k < 16; ++k) {
      double acc = 0.0;
      for (int l = 1; l < s; ++l) acc += At[s][l]*C[l][k-1];
      C[s][k] = acc;
    }
  }
  double M[16]; memset(M, 0, sizeof(M)); M[0] = 1.0;
  for (int k = 1; k < 16; ++k) {
    double acc = 0.0;
    for (int s = 1; s <= 6; ++s) acc += dB[s]*C[s][k-1];
    M[k] = acc;
  }
  double p64m[16]; p64m[0] = 1.0;
  for (int m = 1; m < 16; ++m) p64m[m] = p64m[m-1]*64.0;

  // harvest scaled coefficient rows of M^n along one pmul chain
  CFX cfx; memset(&cfx, 0, sizeof(cfx));
  CMB cmb; memset(&cmb, 0, sizeof(cmb));
  double cur[16]; memset(cur, 0, sizeof(cur)); cur[0] = 1.0;
  for (int n = 0; n <= 4032; ++n) {
    if (n < 64)  for (int m = 0; m <= 4; ++m) cfx.cf[n][m] = (float)(cur[m]/p64m[m]);
    if ((n & 63) == 0) {
      int j = n >> 6;
      if (j < 64) for (int m = 0; m <= 6; ++m) cfx.cx[j][m] = (float)(cur[m]/p64m[m]);
    }
    if ((n & 255) == 0) {
      int J = n >> 8;
      if (J <= 15) for (int m = 0; m <= 6; ++m) cmb.c[J][m] = (float)(cur[m]/p64m[m]);
    }
    if ((n & 255) == 128) {
      int J = (n - 128) >> 8;
      if (J <= 14) for (int m = 0; m <= 6; ++m) cmb.c[16+J][m] = (float)(cur[m]/p64m[m]);
    }
    pmul16(cur, M, cur);
  }

  // EK: [z^m](M-1)^k / 64^m for phase2's closed-form M^i coefficients
  EK ek; memset(&ek, 0, sizeof(ek));
  {
    double e1[5] = {0,0,0,0,0}, e2[5] = {0,0,0,0,0}, e3[5] = {0,0,0,0,0}, e4[5] = {0,0,0,0,0};
    for (int m = 1; m <= 4; ++m) e1[m] = M[m];
    for (int m = 2; m <= 4; ++m) for (int a = 1; a < m; ++a) e2[m] += e1[a]*e1[m-a];
    for (int m = 3; m <= 4; ++m) for (int a = 2; a < m; ++a) e3[m] += e2[a]*e1[m-a];
    e4[4] = e3[3]*e1[1];
    for (int m = 1; m <= 4; ++m) {
      ek.e[0][m-1] = e1[m]/p64m[m];
      ek.e[1][m-1] = e2[m]/p64m[m];
      ek.e[2][m-1] = e3[m]/p64m[m];
      ek.e[3][m-1] = e4[m]/p64m[m];
    }
  }

  k_vchain<<<309, 256, 0, stream>>>(y0, Bm, ws, out, cmb);
  k_phi<<<120, 256, 0, stream>>>(ws);
  k_phase2<<<64, 256, 0, stream>>>(ws, out, ek);
  k_fill<<<1024, 256, 0, stream>>>(ws, out, cfx);
}